// Round 1
// baseline (4809.931 us; speedup 1.0000x reference)
//
#include <hip/hip_runtime.h>
#include <math.h>

#define TYPE_VOCAB 30
#define TOPK 50
#define NUM_TYPE 10
#define NB 512
#define NTOT 200000
#define DIN_I 1024
#define DIN_S 300
#define PDIM 256
#define CHUNK 25600
#define CAP 28

__device__ __forceinline__ float gelu_exact(float x) {
    return 0.5f * x * (1.0f + erff(x * 0.70710678118654752440f));
}

__device__ __forceinline__ bool key_gt(float v1, int i1, float v2, int i2) {
    return (v1 > v2) || (v1 == v2 && i1 < i2);
}

// Fused ProjectionHead + LayerNorm + L2 normalize.
// Block: 256 threads, 32 rows per block. Thread (ty,tx) owns rows {ty*2, ty*2+1},
// cols {j4*64 + tx*4 + q}.
__global__ __launch_bounds__(256) void proj_head_kernel(
    const float* __restrict__ X, int nrows, int din,
    const float* __restrict__ W1, const float* __restrict__ B1,
    const float* __restrict__ W2, const float* __restrict__ B2,
    const float* __restrict__ Gm, const float* __restrict__ Bt,
    float* __restrict__ Y)
{
    __shared__ float Ws[32][PDIM];   // 32 KiB: weight k-chunk
    __shared__ float Gs[32][260];    // 33.3 KiB: gelu(z) tile (pad 260 -> 2-way max)
    __shared__ float Xs[32][33];     // 4.2 KiB: X k-chunk (pad 33 -> conflict-free)

    const int tid = threadIdx.x;
    const int ty = tid >> 4;
    const int tx = tid & 15;
    const int rb = blockIdx.x * 32;
    const int r0 = ty * 2, r1 = r0 + 1;

    float z0[16], z1[16];
#pragma unroll
    for (int j = 0; j < 16; ++j) { z0[j] = 0.f; z1[j] = 0.f; }

    // ---- phase 1: z = X @ W1 ----
    for (int k0 = 0; k0 < din; k0 += 32) {
        {
            const int lrow = tid >> 3;
            const int lk = (tid & 7) * 4;
            const int grow = rb + lrow;
#pragma unroll
            for (int q = 0; q < 4; ++q) {
                int k = k0 + lk + q;
                float v = 0.f;
                if (grow < nrows && k < din) v = X[(size_t)grow * din + k];
                Xs[lrow][lk + q] = v;
            }
        }
#pragma unroll
        for (int q = 0; q < 8; ++q) {
            int flat = q * 1024 + tid * 4;
            int kk = flat >> 8;
            int col = flat & 255;
            float4 v = make_float4(0.f, 0.f, 0.f, 0.f);
            if (k0 + kk < din)
                v = *reinterpret_cast<const float4*>(&W1[(size_t)(k0 + kk) * PDIM + col]);
            *reinterpret_cast<float4*>(&Ws[kk][col]) = v;
        }
        __syncthreads();
#pragma unroll
        for (int kk = 0; kk < 32; ++kk) {
            float a0 = Xs[r0][kk];
            float a1 = Xs[r1][kk];
#pragma unroll
            for (int j4 = 0; j4 < 4; ++j4) {
                float4 w = *reinterpret_cast<const float4*>(&Ws[kk][j4 * 64 + tx * 4]);
                float wv[4] = {w.x, w.y, w.z, w.w};
#pragma unroll
                for (int q = 0; q < 4; ++q) {
                    z0[j4 * 4 + q] = fmaf(a0, wv[q], z0[j4 * 4 + q]);
                    z1[j4 * 4 + q] = fmaf(a1, wv[q], z1[j4 * 4 + q]);
                }
            }
        }
        __syncthreads();
    }

    // ---- z += b1 ; Gs = gelu(z) ----
#pragma unroll
    for (int j4 = 0; j4 < 4; ++j4) {
        int c = j4 * 64 + tx * 4;
        float4 b = *reinterpret_cast<const float4*>(&B1[c]);
        float bv[4] = {b.x, b.y, b.z, b.w};
        float g0v[4], g1v[4];
#pragma unroll
        for (int q = 0; q < 4; ++q) {
            z0[j4 * 4 + q] += bv[q];
            z1[j4 * 4 + q] += bv[q];
            g0v[q] = gelu_exact(z0[j4 * 4 + q]);
            g1v[q] = gelu_exact(z1[j4 * 4 + q]);
        }
        *reinterpret_cast<float4*>(&Gs[r0][c]) = make_float4(g0v[0], g0v[1], g0v[2], g0v[3]);
        *reinterpret_cast<float4*>(&Gs[r1][c]) = make_float4(g1v[0], g1v[1], g1v[2], g1v[3]);
    }

    // ---- phase 2: h2 = gelu(z) @ W2 ----
    float h0[16], h1[16];
#pragma unroll
    for (int j = 0; j < 16; ++j) { h0[j] = 0.f; h1[j] = 0.f; }

    for (int k0 = 0; k0 < PDIM; k0 += 32) {
#pragma unroll
        for (int q = 0; q < 8; ++q) {
            int flat = q * 1024 + tid * 4;
            int kk = flat >> 8;
            int col = flat & 255;
            *reinterpret_cast<float4*>(&Ws[kk][col]) =
                *reinterpret_cast<const float4*>(&W2[(size_t)(k0 + kk) * PDIM + col]);
        }
        __syncthreads();
#pragma unroll
        for (int kk = 0; kk < 32; ++kk) {
            float g0 = Gs[r0][k0 + kk];
            float g1 = Gs[r1][k0 + kk];
#pragma unroll
            for (int j4 = 0; j4 < 4; ++j4) {
                float4 w = *reinterpret_cast<const float4*>(&Ws[kk][j4 * 64 + tx * 4]);
                float wv[4] = {w.x, w.y, w.z, w.w};
#pragma unroll
                for (int q = 0; q < 4; ++q) {
                    h0[j4 * 4 + q] = fmaf(g0, wv[q], h0[j4 * 4 + q]);
                    h1[j4 * 4 + q] = fmaf(g1, wv[q], h1[j4 * 4 + q]);
                }
            }
        }
        __syncthreads();
    }

    // ---- h = h2 + b2 + z ; LayerNorm ; L2 normalize ----
    float s = 0.f, s2 = 0.f, t = 0.f, t2 = 0.f;
#pragma unroll
    for (int j4 = 0; j4 < 4; ++j4) {
        int c = j4 * 64 + tx * 4;
        float4 b = *reinterpret_cast<const float4*>(&B2[c]);
        float bv[4] = {b.x, b.y, b.z, b.w};
#pragma unroll
        for (int q = 0; q < 4; ++q) {
            float v0 = h0[j4 * 4 + q] + bv[q] + z0[j4 * 4 + q];
            float v1 = h1[j4 * 4 + q] + bv[q] + z1[j4 * 4 + q];
            h0[j4 * 4 + q] = v0;
            h1[j4 * 4 + q] = v1;
            s += v0; s2 += v0 * v0;
            t += v1; t2 += v1 * v1;
        }
    }
#pragma unroll
    for (int m = 1; m < 16; m <<= 1) {
        s += __shfl_xor(s, m, 64);  s2 += __shfl_xor(s2, m, 64);
        t += __shfl_xor(t, m, 64);  t2 += __shfl_xor(t2, m, 64);
    }
    float mu0 = s * (1.f / PDIM), mu1 = t * (1.f / PDIM);
    float var0 = s2 * (1.f / PDIM) - mu0 * mu0;
    float var1 = t2 * (1.f / PDIM) - mu1 * mu1;
    float rs0 = 1.f / sqrtf(var0 + 1e-5f);
    float rs1 = 1.f / sqrtf(var1 + 1e-5f);

    float n0 = 0.f, n1 = 0.f;
#pragma unroll
    for (int j4 = 0; j4 < 4; ++j4) {
        int c = j4 * 64 + tx * 4;
        float4 g = *reinterpret_cast<const float4*>(&Gm[c]);
        float4 be = *reinterpret_cast<const float4*>(&Bt[c]);
        float gv[4] = {g.x, g.y, g.z, g.w};
        float bev[4] = {be.x, be.y, be.z, be.w};
#pragma unroll
        for (int q = 0; q < 4; ++q) {
            float u0 = gv[q] * (h0[j4 * 4 + q] - mu0) * rs0 + bev[q];
            float u1 = gv[q] * (h1[j4 * 4 + q] - mu1) * rs1 + bev[q];
            h0[j4 * 4 + q] = u0;
            h1[j4 * 4 + q] = u1;
            n0 += u0 * u0; n1 += u1 * u1;
        }
    }
#pragma unroll
    for (int m = 1; m < 16; m <<= 1) {
        n0 += __shfl_xor(n0, m, 64);
        n1 += __shfl_xor(n1, m, 64);
    }
    float inv0 = 1.f / fmaxf(sqrtf(n0), 1e-12f);
    float inv1 = 1.f / fmaxf(sqrtf(n1), 1e-12f);

    const int gr0 = rb + r0, gr1 = rb + r1;
#pragma unroll
    for (int j4 = 0; j4 < 4; ++j4) {
        int c = j4 * 64 + tx * 4;
        if (gr0 < nrows) {
            *reinterpret_cast<float4*>(&Y[(size_t)gr0 * PDIM + c]) =
                make_float4(h0[j4 * 4] * inv0, h0[j4 * 4 + 1] * inv0,
                            h0[j4 * 4 + 2] * inv0, h0[j4 * 4 + 3] * inv0);
        }
        if (gr1 < nrows) {
            *reinterpret_cast<float4*>(&Y[(size_t)gr1 * PDIM + c]) =
                make_float4(h1[j4 * 4] * inv1, h1[j4 * 4 + 1] * inv1,
                            h1[j4 * 4 + 2] * inv1, h1[j4 * 4 + 3] * inv1);
        }
    }
}

// sim = A [512,256] @ Bm [nrows,256]^T  -> C [512, nrows] (ldc = nrows)
// 128x128 tile, 256 threads, 8x8 acc per thread.
__global__ __launch_bounds__(256) void sim_gemm_kernel(
    const float* __restrict__ A, const float* __restrict__ Bm,
    int nrows, float* __restrict__ C)
{
    __shared__ float As[32][132];   // [kk][row], pad 132
    __shared__ float Bs[32][132];

    const int tid = threadIdx.x;
    const int tyy = tid >> 4, txx = tid & 15;
    const int rowbase = blockIdx.y * 128;
    const int colbase = blockIdx.x * 128;

    float acc[8][8];
#pragma unroll
    for (int i = 0; i < 8; ++i)
#pragma unroll
        for (int j = 0; j < 8; ++j) acc[i][j] = 0.f;

    for (int k0 = 0; k0 < PDIM; k0 += 32) {
#pragma unroll
        for (int q = 0; q < 4; ++q) {
            int flat = q * 1024 + tid * 4;
            int lrow = flat >> 5;
            int kk = flat & 31;
            float4 av = *reinterpret_cast<const float4*>(
                &A[(size_t)(rowbase + lrow) * PDIM + k0 + kk]);
            As[kk + 0][lrow] = av.x; As[kk + 1][lrow] = av.y;
            As[kk + 2][lrow] = av.z; As[kk + 3][lrow] = av.w;
            int grow = colbase + lrow;
            float4 bv = make_float4(0.f, 0.f, 0.f, 0.f);
            if (grow < nrows)
                bv = *reinterpret_cast<const float4*>(&Bm[(size_t)grow * PDIM + k0 + kk]);
            Bs[kk + 0][lrow] = bv.x; Bs[kk + 1][lrow] = bv.y;
            Bs[kk + 2][lrow] = bv.z; Bs[kk + 3][lrow] = bv.w;
        }
        __syncthreads();
#pragma unroll
        for (int kk = 0; kk < 32; ++kk) {
            float4 a0 = *reinterpret_cast<const float4*>(&As[kk][tyy * 8]);
            float4 a1 = *reinterpret_cast<const float4*>(&As[kk][tyy * 8 + 4]);
            float4 b0 = *reinterpret_cast<const float4*>(&Bs[kk][txx * 4]);
            float4 b1 = *reinterpret_cast<const float4*>(&Bs[kk][64 + txx * 4]);
            float a[8] = {a0.x, a0.y, a0.z, a0.w, a1.x, a1.y, a1.z, a1.w};
            float b[8] = {b0.x, b0.y, b0.z, b0.w, b1.x, b1.y, b1.z, b1.w};
#pragma unroll
            for (int i = 0; i < 8; ++i)
#pragma unroll
                for (int j = 0; j < 8; ++j)
                    acc[i][j] = fmaf(a[i], b[j], acc[i][j]);
        }
        __syncthreads();
    }

#pragma unroll
    for (int i = 0; i < 8; ++i) {
        int r = rowbase + tyy * 8 + i;
#pragma unroll
        for (int j4 = 0; j4 < 2; ++j4) {
            int c = colbase + j4 * 64 + txx * 4;
            if (c < nrows) {
                *reinterpret_cast<float4*>(&C[(size_t)r * nrows + c]) =
                    make_float4(acc[i][j4 * 4 + 0], acc[i][j4 * 4 + 1],
                                acc[i][j4 * 4 + 2], acc[i][j4 * 4 + 3]);
            }
        }
    }
}

// Per-row running top-50 merge. One block per image row. Per-thread sorted
// candidate lists in LDS; 50 rounds of wave-shuffle argmax extraction.
// Key order: (val desc, global idx asc) == jax.lax.top_k tie-break.
__global__ __launch_bounds__(256) void topk_merge_kernel(
    const float* __restrict__ C, int ldc, int ncols, int nbase,
    float* __restrict__ stateV, int* __restrict__ stateI, int first)
{
    __shared__ float lv[256 * CAP];
    __shared__ int   li[256 * CAP];
    __shared__ float wrv[4];
    __shared__ int   wri[4];
    __shared__ int   wrt[4];
    __shared__ int   winnerS;
    __shared__ float outV[TOPK];
    __shared__ int   outI[TOPK];

    const int tid = threadIdx.x;
    const int b = blockIdx.x;
    const int off = tid * CAP;
    int cnt = 0;

    auto ins = [&](float v, int gi) {
        if (cnt == CAP) {
            if (!key_gt(v, gi, lv[off + CAP - 1], li[off + CAP - 1])) return;
            int p = CAP - 1;
            while (p > 0 && key_gt(v, gi, lv[off + p - 1], li[off + p - 1])) {
                lv[off + p] = lv[off + p - 1];
                li[off + p] = li[off + p - 1];
                --p;
            }
            lv[off + p] = v; li[off + p] = gi;
        } else {
            int p = cnt;
            while (p > 0 && key_gt(v, gi, lv[off + p - 1], li[off + p - 1])) {
                lv[off + p] = lv[off + p - 1];
                li[off + p] = li[off + p - 1];
                --p;
            }
            lv[off + p] = v; li[off + p] = gi;
            ++cnt;
        }
    };

    if (!first && tid < TOPK) ins(stateV[b * TOPK + tid], stateI[b * TOPK + tid]);
    for (int e = tid; e < ncols; e += 256) ins(C[(size_t)b * ldc + e], nbase + e);

    __syncthreads();

    int head = 0;
    for (int r = 0; r < TOPK; ++r) {
        float hv; int hi;
        if (head < cnt) { hv = lv[off + head]; hi = li[off + head]; }
        else { hv = -3.402823466e38f; hi = 0x7fffffff; }
        int ht = tid;
#pragma unroll
        for (int m = 32; m > 0; m >>= 1) {
            float ov = __shfl_xor(hv, m, 64);
            int oi = __shfl_xor(hi, m, 64);
            int ot = __shfl_xor(ht, m, 64);
            if (key_gt(ov, oi, hv, hi)) { hv = ov; hi = oi; ht = ot; }
        }
        if ((tid & 63) == 0) { int w = tid >> 6; wrv[w] = hv; wri[w] = hi; wrt[w] = ht; }
        __syncthreads();
        if (tid == 0) {
            float bv = wrv[0]; int bi = wri[0]; int bt = wrt[0];
#pragma unroll
            for (int w = 1; w < 4; ++w)
                if (key_gt(wrv[w], wri[w], bv, bi)) { bv = wrv[w]; bi = wri[w]; bt = wrt[w]; }
            outV[r] = bv; outI[r] = bi; winnerS = bt;
        }
        __syncthreads();
        if (tid == winnerS) ++head;
    }
    __syncthreads();
    if (tid < TOPK) {
        stateV[b * TOPK + tid] = outV[tid];
        stateI[b * TOPK + tid] = outI[tid];
    }
}

// Histogram -> top-10 types (count desc, id asc, count>0) -> keep mask ->
// weighted mean of gathered all_expr rows; conf mask.
__global__ __launch_bounds__(256) void finalize_kernel(
    const float* __restrict__ stateV, const int* __restrict__ stateI,
    const int* __restrict__ ctype, const float* __restrict__ all_expr,
    float* __restrict__ out)
{
    const int b = blockIdx.x;
    const int tid = threadIdx.x;
    __shared__ int s_idx[TOPK];
    __shared__ int s_type[TOPK];
    __shared__ int s_keep[TOPK];
    __shared__ int s_cnt[TYPE_VOCAB];
    __shared__ unsigned s_keptmask;
    __shared__ float s_wsum;

    if (tid < TYPE_VOCAB) s_cnt[tid] = 0;
    __syncthreads();
    if (tid < TOPK) {
        int gi = stateI[b * TOPK + tid];
        s_idx[tid] = gi;
        int tpe = ctype[gi];
        s_type[tid] = tpe;
        atomicAdd(&s_cnt[tpe], 1);
    }
    __syncthreads();
    if (tid == 0) {
        unsigned kept = 0, used = 0;
        for (int r = 0; r < NUM_TYPE; ++r) {
            int bc = -1, bt = -1;
            for (int tt = 0; tt < TYPE_VOCAB; ++tt) {
                if (used & (1u << tt)) continue;
                if (s_cnt[tt] > bc) { bc = s_cnt[tt]; bt = tt; }
            }
            used |= 1u << bt;
            if (bc > 0) kept |= 1u << bt;
        }
        s_keptmask = kept;
        float sum = 0.f;
        for (int k = 0; k < TOPK; ++k) sum += stateV[b * TOPK + k];
        out[b] = (sum * (1.f / TOPK) > 0.1f) ? 1.0f : 0.0f;
    }
    __syncthreads();
    if (tid < TOPK) s_keep[tid] = (s_keptmask >> s_type[tid]) & 1u;
    __syncthreads();
    if (tid == 0) {
        int w = 0;
        for (int k = 0; k < TOPK; ++k) w += s_keep[k];
        s_wsum = (float)w;
    }
    __syncthreads();
    float wsum = s_wsum;
    for (int d = tid; d < DIN_S; d += 256) {
        float sacc = 0.f;
        for (int k = 0; k < TOPK; ++k)
            if (s_keep[k]) sacc += all_expr[(size_t)s_idx[k] * DIN_S + d];
        out[NB + (size_t)b * DIN_S + d] = sacc / wsum;
    }
}

extern "C" void kernel_launch(void* const* d_in, const int* in_sizes, int n_in,
                              void* d_out, int out_size, void* d_ws, size_t ws_size,
                              hipStream_t stream)
{
    const float* feature       = (const float*)d_in[0];
    const float* all_expr      = (const float*)d_in[1];
    const int*   all_cell_type = (const int*)d_in[2];
    const float* iw1 = (const float*)d_in[3];
    const float* ib1 = (const float*)d_in[4];
    const float* iw2 = (const float*)d_in[5];
    const float* ib2 = (const float*)d_in[6];
    const float* ig  = (const float*)d_in[7];
    const float* ibt = (const float*)d_in[8];
    const float* sw1 = (const float*)d_in[9];
    const float* sb1 = (const float*)d_in[10];
    const float* sw2 = (const float*)d_in[11];
    const float* sb2 = (const float*)d_in[12];
    const float* sg  = (const float*)d_in[13];
    const float* sbt = (const float*)d_in[14];

    float* ws = (float*)d_ws;
    float* img_norm   = ws;                                    // 512*256
    float* expr_chunk = img_norm + (size_t)NB * PDIM;          // CHUNK*256
    float* sim_chunk  = expr_chunk + (size_t)CHUNK * PDIM;     // 512*CHUNK
    float* stateV     = sim_chunk + (size_t)NB * CHUNK;        // 512*50
    int*   stateI     = (int*)(stateV + (size_t)NB * TOPK);    // 512*50

    // image projection head (tiny: 16 blocks)
    proj_head_kernel<<<NB / 32, 256, 0, stream>>>(
        feature, NB, DIN_I, iw1, ib1, iw2, ib2, ig, ibt, img_norm);

    int chunk_i = 0;
    for (int c0 = 0; c0 < NTOT; c0 += CHUNK, ++chunk_i) {
        int rows = (NTOT - c0 < CHUNK) ? (NTOT - c0) : CHUNK;

        proj_head_kernel<<<(rows + 31) / 32, 256, 0, stream>>>(
            all_expr + (size_t)c0 * DIN_S, rows, DIN_S,
            sw1, sb1, sw2, sb2, sg, sbt, expr_chunk);

        dim3 g((rows + 127) / 128, NB / 128);
        sim_gemm_kernel<<<g, 256, 0, stream>>>(img_norm, expr_chunk, rows, sim_chunk);

        topk_merge_kernel<<<NB, 256, 0, stream>>>(
            sim_chunk, rows, rows, c0, stateV, stateI, chunk_i == 0 ? 1 : 0);
    }

    finalize_kernel<<<NB, 256, 0, stream>>>(
        stateV, stateI, all_cell_type, all_expr, (float*)d_out);
}

// Round 3
// 3799.275 us; speedup vs baseline: 1.2660x; 1.2660x over previous
//
#include <hip/hip_runtime.h>
#include <math.h>

#define TYPE_VOCAB 30
#define TOPK 50
#define NUM_TYPE 10
#define NB 512
#define NTOT 200000
#define DIN_I 1024
#define DIN_S 300
#define PDIM 256
#define CHUNK 25600
#define NCHUNK 8
#define PRE 2048
#define SCAP 7616        // survivor capacity per row (expected ~600 max at chunk0)
#define MERGE_CAP 120    // 64 threads * 120 >= SCAP + 50 exactly
#define ICAP 28

__device__ __forceinline__ float gelu_exact(float x) {
    return 0.5f * x * (1.0f + erff(x * 0.70710678118654752440f));
}

// (val desc, idx asc) — matches jax.lax.top_k tie-break
__device__ __forceinline__ bool key_gt(float v1, int i1, float v2, int i2) {
    return (v1 > v2) || (v1 == v2 && i1 < i2);
}

// ============================================================================
// Fused ProjectionHead + LayerNorm + L2 normalize.
// 256 threads, 64 rows/block. Thread (tyy,txx): rows tyy*4+i, cols j4*64+txx*4+q.
// Per kk: 80 B LDS for 64 FMA (1.25 B/FMA).
// LDS: Ws 32K + GXs 17.4K = 49 KB -> 2+ blocks/CU.
// ============================================================================
__global__ __launch_bounds__(256) void proj_head_kernel(
    const float* __restrict__ X, int nrows, int din,
    const float* __restrict__ W1, const float* __restrict__ B1,
    const float* __restrict__ W2, const float* __restrict__ B2,
    const float* __restrict__ Gm, const float* __restrict__ Bt,
    float* __restrict__ Y)
{
    __shared__ float Ws[32][PDIM];   // weight k-chunk [kk][col]
    __shared__ float GXs[64][68];    // phase1: XsT[kk][row] (rows 0..31); phase2: GsT[klocal][row]

    const int tid = threadIdx.x;
    const int txx = tid & 15;
    const int tyy = tid >> 4;        // 0..15
    const int rb = blockIdx.x * 64;

    float z[4][16];
#pragma unroll
    for (int i = 0; i < 4; ++i)
#pragma unroll
        for (int j = 0; j < 16; ++j) z[i][j] = 0.f;

    // ---- phase 1: z = X @ W1 ----
    for (int k0 = 0; k0 < din; k0 += 32) {
        // stage XsT: 64 rows x 32 k, transposed [k][row]
#pragma unroll
        for (int q = 0; q < 2; ++q) {
            int flat = q * 256 + tid;
            int row = flat & 63;
            int kq = flat >> 6;            // 0..7
            int grow = rb + row;
            float4 v = make_float4(0.f, 0.f, 0.f, 0.f);
            if (grow < nrows && (k0 + kq * 4 + 4) <= din)
                v = *reinterpret_cast<const float4*>(&X[(size_t)grow * din + k0 + kq * 4]);
            GXs[kq * 4 + 0][row] = v.x;
            GXs[kq * 4 + 1][row] = v.y;
            GXs[kq * 4 + 2][row] = v.z;
            GXs[kq * 4 + 3][row] = v.w;
        }
        // stage Ws (32 x 256)
#pragma unroll
        for (int q = 0; q < 8; ++q) {
            int flat = q * 1024 + tid * 4;
            int kk = flat >> 8;
            int col = flat & 255;
            float4 v = make_float4(0.f, 0.f, 0.f, 0.f);
            if (k0 + kk < din)
                v = *reinterpret_cast<const float4*>(&W1[(size_t)(k0 + kk) * PDIM + col]);
            *reinterpret_cast<float4*>(&Ws[kk][col]) = v;
        }
        __syncthreads();
#pragma unroll 8
        for (int kk = 0; kk < 32; ++kk) {
            float4 a = *reinterpret_cast<const float4*>(&GXs[kk][tyy * 4]);
            float av[4] = {a.x, a.y, a.z, a.w};
#pragma unroll
            for (int j4 = 0; j4 < 4; ++j4) {
                float4 w = *reinterpret_cast<const float4*>(&Ws[kk][j4 * 64 + txx * 4]);
                float wv[4] = {w.x, w.y, w.z, w.w};
#pragma unroll
                for (int i = 0; i < 4; ++i)
#pragma unroll
                    for (int q = 0; q < 4; ++q)
                        z[i][j4 * 4 + q] = fmaf(av[i], wv[q], z[i][j4 * 4 + q]);
            }
        }
        __syncthreads();
    }

    // z += b1
#pragma unroll
    for (int j4 = 0; j4 < 4; ++j4) {
        float4 b = *reinterpret_cast<const float4*>(&B1[j4 * 64 + txx * 4]);
        float bv[4] = {b.x, b.y, b.z, b.w};
#pragma unroll
        for (int i = 0; i < 4; ++i)
#pragma unroll
            for (int q = 0; q < 4; ++q) z[i][j4 * 4 + q] += bv[q];
    }

    // ---- phase 2: h = gelu(z) @ W2, processed in 4 k-quarters of 64 ----
    float h[4][16];
#pragma unroll
    for (int i = 0; i < 4; ++i)
#pragma unroll
        for (int j = 0; j < 16; ++j) h[i][j] = 0.f;

    for (int kq2 = 0; kq2 < 4; ++kq2) {
        // write GsT for this quarter: this thread's cols with j4 == kq2
#pragma unroll
        for (int qq = 0; qq < 4; ++qq)
#pragma unroll
            for (int i = 0; i < 4; ++i)
                GXs[txx * 4 + qq][tyy * 4 + i] = gelu_exact(z[i][kq2 * 4 + qq]);

#pragma unroll
        for (int half = 0; half < 2; ++half) {
            int k0 = kq2 * 64 + half * 32;
#pragma unroll
            for (int q = 0; q < 8; ++q) {
                int flat = q * 1024 + tid * 4;
                int kk = flat >> 8;
                int col = flat & 255;
                *reinterpret_cast<float4*>(&Ws[kk][col]) =
                    *reinterpret_cast<const float4*>(&W2[(size_t)(k0 + kk) * PDIM + col]);
            }
            __syncthreads();
#pragma unroll 8
            for (int kk = 0; kk < 32; ++kk) {
                float4 g = *reinterpret_cast<const float4*>(&GXs[half * 32 + kk][tyy * 4]);
                float gv[4] = {g.x, g.y, g.z, g.w};
#pragma unroll
                for (int j4 = 0; j4 < 4; ++j4) {
                    float4 w = *reinterpret_cast<const float4*>(&Ws[kk][j4 * 64 + txx * 4]);
                    float wv[4] = {w.x, w.y, w.z, w.w};
#pragma unroll
                    for (int i = 0; i < 4; ++i)
#pragma unroll
                        for (int q = 0; q < 4; ++q)
                            h[i][j4 * 4 + q] = fmaf(gv[i], wv[q], h[i][j4 * 4 + q]);
                }
            }
            __syncthreads();
        }
    }

    // ---- h = h + b2 + z ; LayerNorm ; L2 normalize ; store ----
    float s[4] = {0.f, 0.f, 0.f, 0.f}, s2[4] = {0.f, 0.f, 0.f, 0.f};
#pragma unroll
    for (int j4 = 0; j4 < 4; ++j4) {
        float4 b = *reinterpret_cast<const float4*>(&B2[j4 * 64 + txx * 4]);
        float bv[4] = {b.x, b.y, b.z, b.w};
#pragma unroll
        for (int i = 0; i < 4; ++i)
#pragma unroll
            for (int q = 0; q < 4; ++q) {
                float v = h[i][j4 * 4 + q] + bv[q] + z[i][j4 * 4 + q];
                h[i][j4 * 4 + q] = v;
                s[i] += v;
                s2[i] += v * v;
            }
    }
#pragma unroll
    for (int m = 1; m < 16; m <<= 1)
#pragma unroll
        for (int i = 0; i < 4; ++i) {
            s[i] += __shfl_xor(s[i], m, 64);
            s2[i] += __shfl_xor(s2[i], m, 64);
        }
    float rs[4], mu[4];
#pragma unroll
    for (int i = 0; i < 4; ++i) {
        mu[i] = s[i] * (1.f / PDIM);
        float var = s2[i] * (1.f / PDIM) - mu[i] * mu[i];
        rs[i] = 1.f / sqrtf(var + 1e-5f);
    }
    float nn[4] = {0.f, 0.f, 0.f, 0.f};
#pragma unroll
    for (int j4 = 0; j4 < 4; ++j4) {
        float4 g = *reinterpret_cast<const float4*>(&Gm[j4 * 64 + txx * 4]);
        float4 be = *reinterpret_cast<const float4*>(&Bt[j4 * 64 + txx * 4]);
        float gv[4] = {g.x, g.y, g.z, g.w};
        float bev[4] = {be.x, be.y, be.z, be.w};
#pragma unroll
        for (int i = 0; i < 4; ++i)
#pragma unroll
            for (int q = 0; q < 4; ++q) {
                float u = gv[q] * (h[i][j4 * 4 + q] - mu[i]) * rs[i] + bev[q];
                h[i][j4 * 4 + q] = u;
                nn[i] += u * u;
            }
    }
#pragma unroll
    for (int m = 1; m < 16; m <<= 1)
#pragma unroll
        for (int i = 0; i < 4; ++i) nn[i] += __shfl_xor(nn[i], m, 64);
#pragma unroll
    for (int i = 0; i < 4; ++i) {
        float inv = 1.f / fmaxf(sqrtf(nn[i]), 1e-12f);
        int grow = rb + tyy * 4 + i;
        if (grow < nrows) {
#pragma unroll
            for (int j4 = 0; j4 < 4; ++j4) {
                *reinterpret_cast<float4*>(&Y[(size_t)grow * PDIM + j4 * 64 + txx * 4]) =
                    make_float4(h[i][j4 * 4] * inv, h[i][j4 * 4 + 1] * inv,
                                h[i][j4 * 4 + 2] * inv, h[i][j4 * 4 + 3] * inv);
            }
        }
    }
}

// ============================================================================
// sim = A [512,256] @ Bm[chunk]^T. Tile 128 rows x 256 cols, 256 threads,
// 8x16 acc per thread (0.75 B LDS / FMA).
// mode 0: dense write to C (prepass).  mode 1: threshold filter -> survivors.
// ============================================================================
__global__ __launch_bounds__(256) void sim_gemm_kernel(
    const float* __restrict__ A, const float* __restrict__ Bm,
    int nrows, int colbase0, int gibase, int mode,
    float* __restrict__ C, int ldc,
    const float* __restrict__ stateV, const int* __restrict__ stateI,
    float* __restrict__ survV, int* __restrict__ survI, int* __restrict__ cnt)
{
    __shared__ float As[32][128];   // [kk][row]
    __shared__ float Bs[32][PDIM];  // [kk][col]

    const int tid = threadIdx.x;
    const int txx = tid & 15;
    const int tyy = tid >> 4;       // 0..15
    const int rowbase = blockIdx.y * 128;
    const int cb = colbase0 + blockIdx.x * 256;

    float acc[8][16];
#pragma unroll
    for (int i = 0; i < 8; ++i)
#pragma unroll
        for (int j = 0; j < 16; ++j) acc[i][j] = 0.f;

    for (int k0 = 0; k0 < PDIM; k0 += 32) {
#pragma unroll
        for (int q = 0; q < 4; ++q) {
            int flat = q * 256 + tid;
            int row = flat & 127;
            int kq = flat >> 7;         // 0..7
            float4 v = *reinterpret_cast<const float4*>(
                &A[(size_t)(rowbase + row) * PDIM + k0 + kq * 4]);
            As[kq * 4 + 0][row] = v.x;
            As[kq * 4 + 1][row] = v.y;
            As[kq * 4 + 2][row] = v.z;
            As[kq * 4 + 3][row] = v.w;
        }
#pragma unroll
        for (int q = 0; q < 8; ++q) {
            int flat = q * 256 + tid;
            int brow = flat & 255;
            int kq = flat >> 8;         // 0..7
            int gr = cb + brow;
            float4 v = make_float4(0.f, 0.f, 0.f, 0.f);
            if (gr < nrows)
                v = *reinterpret_cast<const float4*>(&Bm[(size_t)gr * PDIM + k0 + kq * 4]);
            Bs[kq * 4 + 0][brow] = v.x;
            Bs[kq * 4 + 1][brow] = v.y;
            Bs[kq * 4 + 2][brow] = v.z;
            Bs[kq * 4 + 3][brow] = v.w;
        }
        __syncthreads();
#pragma unroll 4
        for (int kk = 0; kk < 32; ++kk) {
            float4 a0 = *reinterpret_cast<const float4*>(&As[kk][tyy * 8]);
            float4 a1 = *reinterpret_cast<const float4*>(&As[kk][tyy * 8 + 4]);
            float av[8] = {a0.x, a0.y, a0.z, a0.w, a1.x, a1.y, a1.z, a1.w};
            float bw[16];
#pragma unroll
            for (int j4 = 0; j4 < 4; ++j4) {
                float4 b = *reinterpret_cast<const float4*>(&Bs[kk][j4 * 64 + txx * 4]);
                bw[j4 * 4 + 0] = b.x; bw[j4 * 4 + 1] = b.y;
                bw[j4 * 4 + 2] = b.z; bw[j4 * 4 + 3] = b.w;
            }
#pragma unroll
            for (int i = 0; i < 8; ++i)
#pragma unroll
                for (int j = 0; j < 16; ++j)
                    acc[i][j] = fmaf(av[i], bw[j], acc[i][j]);
        }
        __syncthreads();
    }

    if (mode == 0) {
#pragma unroll
        for (int i = 0; i < 8; ++i) {
            int ri = rowbase + tyy * 8 + i;
#pragma unroll
            for (int j4 = 0; j4 < 4; ++j4) {
                *reinterpret_cast<float4*>(&C[(size_t)ri * ldc + cb + j4 * 64 + txx * 4]) =
                    make_float4(acc[i][j4 * 4], acc[i][j4 * 4 + 1],
                                acc[i][j4 * 4 + 2], acc[i][j4 * 4 + 3]);
            }
        }
    } else {
#pragma unroll
        for (int i = 0; i < 8; ++i) {
            int ri = rowbase + tyy * 8 + i;
            float tv = stateV[ri * TOPK + TOPK - 1];
            int ti = stateI[ri * TOPK + TOPK - 1];
#pragma unroll
            for (int j = 0; j < 16; ++j) {
                int c = cb + (j >> 2) * 64 + txx * 4 + (j & 3);
                if (c < nrows) {
                    float v = acc[i][j];
                    int gi = gibase + c;
                    if (key_gt(v, gi, tv, ti)) {
                        int pos = atomicAdd(&cnt[ri], 1);
                        if (pos < SCAP) {
                            survV[(size_t)ri * SCAP + pos] = v;
                            survI[(size_t)ri * SCAP + pos] = gi;
                        }
                    }
                }
            }
        }
    }
}

// ============================================================================
// Initial top-50 from the dense prepass matrix (one block per image row).
// Also zeroes the survivor counters for the filtered chunks that follow.
// ============================================================================
__global__ __launch_bounds__(256) void topk_init_kernel(
    const float* __restrict__ C, int ldc, int ncols,
    float* __restrict__ stateV, int* __restrict__ stateI, int* __restrict__ cnt)
{
    __shared__ float lv[256 * ICAP];
    __shared__ int   li[256 * ICAP];
    __shared__ float wrv[4];
    __shared__ int   wri[4];
    __shared__ int   wrt[4];
    __shared__ int   winnerS;
    __shared__ float outV[TOPK];
    __shared__ int   outI[TOPK];

    const int tid = threadIdx.x;
    const int b = blockIdx.x;
    const int off = tid * ICAP;
    int n_l = 0;

    auto ins = [&](float v, int gi) {
        if (n_l == ICAP) {
            if (!key_gt(v, gi, lv[off + ICAP - 1], li[off + ICAP - 1])) return;
            int p = ICAP - 1;
            while (p > 0 && key_gt(v, gi, lv[off + p - 1], li[off + p - 1])) {
                lv[off + p] = lv[off + p - 1];
                li[off + p] = li[off + p - 1];
                --p;
            }
            lv[off + p] = v; li[off + p] = gi;
        } else {
            int p = n_l;
            while (p > 0 && key_gt(v, gi, lv[off + p - 1], li[off + p - 1])) {
                lv[off + p] = lv[off + p - 1];
                li[off + p] = li[off + p - 1];
                --p;
            }
            lv[off + p] = v; li[off + p] = gi;
            ++n_l;
        }
    };

    for (int e = tid; e < ncols; e += 256) ins(C[(size_t)b * ldc + e], e);
    __syncthreads();

    int head = 0;
    for (int r = 0; r < TOPK; ++r) {
        float hv; int hi;
        if (head < n_l) { hv = lv[off + head]; hi = li[off + head]; }
        else { hv = -3.402823466e38f; hi = 0x7fffffff; }
        int ht = tid;
#pragma unroll
        for (int m = 32; m > 0; m >>= 1) {
            float ov = __shfl_xor(hv, m, 64);
            int oi = __shfl_xor(hi, m, 64);
            int ot = __shfl_xor(ht, m, 64);
            if (key_gt(ov, oi, hv, hi)) { hv = ov; hi = oi; ht = ot; }
        }
        if ((tid & 63) == 0) { int w = tid >> 6; wrv[w] = hv; wri[w] = hi; wrt[w] = ht; }
        __syncthreads();
        if (tid == 0) {
            float bv = wrv[0]; int bi = wri[0]; int bt = wrt[0];
#pragma unroll
            for (int w = 1; w < 4; ++w)
                if (key_gt(wrv[w], wri[w], bv, bi)) { bv = wrv[w]; bi = wri[w]; bt = wrt[w]; }
            outV[r] = bv; outI[r] = bi; winnerS = bt;
        }
        __syncthreads();
        if (tid == winnerS) ++head;
    }
    __syncthreads();
    if (tid < TOPK) {
        stateV[b * TOPK + tid] = outV[tid];
        stateI[b * TOPK + tid] = outI[tid];
    }
    if (tid == 0) cnt[b] = 0;
}

// ============================================================================
// Merge survivors into running top-50 state. One 64-thread wave per row —
// no barriers needed. Zeroes cnt for the next chunk.
// ============================================================================
__global__ __launch_bounds__(64) void surv_merge_kernel(
    const float* __restrict__ survV, const int* __restrict__ survI,
    int* __restrict__ cnt,
    float* __restrict__ stateV, int* __restrict__ stateI)
{
    __shared__ float lv[64 * MERGE_CAP];
    __shared__ int   li[64 * MERGE_CAP];

    const int tid = threadIdx.x;
    const int b = blockIdx.x;
    int n = cnt[b];
    if (n > SCAP) n = SCAP;
    const int off = tid * MERGE_CAP;
    int n_l = 0;

    auto ins = [&](float v, int gi) {
        if (n_l == MERGE_CAP) {
            if (!key_gt(v, gi, lv[off + MERGE_CAP - 1], li[off + MERGE_CAP - 1])) return;
            int p = MERGE_CAP - 1;
            while (p > 0 && key_gt(v, gi, lv[off + p - 1], li[off + p - 1])) {
                lv[off + p] = lv[off + p - 1];
                li[off + p] = li[off + p - 1];
                --p;
            }
            lv[off + p] = v; li[off + p] = gi;
        } else {
            int p = n_l;
            while (p > 0 && key_gt(v, gi, lv[off + p - 1], li[off + p - 1])) {
                lv[off + p] = lv[off + p - 1];
                li[off + p] = li[off + p - 1];
                --p;
            }
            lv[off + p] = v; li[off + p] = gi;
            ++n_l;
        }
    };

    if (tid < TOPK) ins(stateV[b * TOPK + tid], stateI[b * TOPK + tid]);
    for (int e = tid; e < n; e += 64)
        ins(survV[(size_t)b * SCAP + e], survI[(size_t)b * SCAP + e]);

    int head = 0;
    float myV = 0.f; int myI = 0;
    for (int r = 0; r < TOPK; ++r) {
        float hv; int hi;
        if (head < n_l) { hv = lv[off + head]; hi = li[off + head]; }
        else { hv = -3.402823466e38f; hi = 0x7fffffff; }
        int ht = tid;
#pragma unroll
        for (int m = 1; m < 64; m <<= 1) {
            float ov = __shfl_xor(hv, m, 64);
            int oi = __shfl_xor(hi, m, 64);
            int ot = __shfl_xor(ht, m, 64);
            if (key_gt(ov, oi, hv, hi)) { hv = ov; hi = oi; ht = ot; }
        }
        if (tid == ht) ++head;
        if (tid == r) { myV = hv; myI = hi; }
    }
    if (tid < TOPK) {
        stateV[b * TOPK + tid] = myV;
        stateI[b * TOPK + tid] = myI;
    }
    if (tid == 0) cnt[b] = 0;
}

// ============================================================================
// Histogram -> top-10 types (count desc, id asc, count>0) -> keep mask ->
// weighted mean of gathered all_expr rows; conf mask.
// ============================================================================
__global__ __launch_bounds__(256) void finalize_kernel(
    const float* __restrict__ stateV, const int* __restrict__ stateI,
    const int* __restrict__ ctype, const float* __restrict__ all_expr,
    float* __restrict__ out)
{
    const int b = blockIdx.x;
    const int tid = threadIdx.x;
    __shared__ int s_idx[TOPK];
    __shared__ int s_type[TOPK];
    __shared__ int s_keep[TOPK];
    __shared__ int s_cnt[TYPE_VOCAB];
    __shared__ unsigned s_keptmask;
    __shared__ float s_wsum;

    if (tid < TYPE_VOCAB) s_cnt[tid] = 0;
    __syncthreads();
    if (tid < TOPK) {
        int gi = stateI[b * TOPK + tid];
        s_idx[tid] = gi;
        int tpe = ctype[gi];
        s_type[tid] = tpe;
        atomicAdd(&s_cnt[tpe], 1);
    }
    __syncthreads();
    if (tid == 0) {
        unsigned kept = 0, used = 0;
        for (int r = 0; r < NUM_TYPE; ++r) {
            int bc = -1, bt = -1;
            for (int tt = 0; tt < TYPE_VOCAB; ++tt) {
                if (used & (1u << tt)) continue;
                if (s_cnt[tt] > bc) { bc = s_cnt[tt]; bt = tt; }
            }
            used |= 1u << bt;
            if (bc > 0) kept |= 1u << bt;
        }
        s_keptmask = kept;
        float sum = 0.f;
        for (int k = 0; k < TOPK; ++k) sum += stateV[b * TOPK + k];
        out[b] = (sum * (1.f / TOPK) > 0.1f) ? 1.0f : 0.0f;
    }
    __syncthreads();
    if (tid < TOPK) s_keep[tid] = (s_keptmask >> s_type[tid]) & 1u;
    __syncthreads();
    if (tid == 0) {
        int w = 0;
        for (int k = 0; k < TOPK; ++k) w += s_keep[k];
        s_wsum = (float)w;
    }
    __syncthreads();
    float wsum = s_wsum;
    for (int d = tid; d < DIN_S; d += 256) {
        float sacc = 0.f;
        for (int k = 0; k < TOPK; ++k)
            if (s_keep[k]) sacc += all_expr[(size_t)s_idx[k] * DIN_S + d];
        out[NB + (size_t)b * DIN_S + d] = sacc / wsum;
    }
}

extern "C" void kernel_launch(void* const* d_in, const int* in_sizes, int n_in,
                              void* d_out, int out_size, void* d_ws, size_t ws_size,
                              hipStream_t stream)
{
    const float* feature       = (const float*)d_in[0];
    const float* all_expr      = (const float*)d_in[1];
    const int*   all_cell_type = (const int*)d_in[2];
    const float* iw1 = (const float*)d_in[3];
    const float* ib1 = (const float*)d_in[4];
    const float* iw2 = (const float*)d_in[5];
    const float* ib2 = (const float*)d_in[6];
    const float* ig  = (const float*)d_in[7];
    const float* ibt = (const float*)d_in[8];
    const float* sw1 = (const float*)d_in[9];
    const float* sb1 = (const float*)d_in[10];
    const float* sw2 = (const float*)d_in[11];
    const float* sb2 = (const float*)d_in[12];
    const float* sg  = (const float*)d_in[13];
    const float* sbt = (const float*)d_in[14];

    float* ws = (float*)d_ws;
    float* img_norm   = ws;                                       // 512*256
    float* expr_chunk = img_norm + (size_t)NB * PDIM;             // 25600*256
    float* sim_pre    = expr_chunk + (size_t)CHUNK * PDIM;        // 512*2048
    float* stateV     = sim_pre + (size_t)NB * PRE;               // 512*50
    int*   stateI     = (int*)(stateV + (size_t)NB * TOPK);       // 512*50
    float* survV      = (float*)(stateI + (size_t)NB * TOPK);     // 512*SCAP
    int*   survI      = (int*)(survV + (size_t)NB * SCAP);        // 512*SCAP
    int*   cnt        = survI + (size_t)NB * SCAP;                // 512

    // projection heads
    proj_head_kernel<<<NB / 64, 256, 0, stream>>>(
        feature, NB, DIN_I, iw1, ib1, iw2, ib2, ig, ibt, img_norm);
    proj_head_kernel<<<CHUNK / 64, 256, 0, stream>>>(
        all_expr, CHUNK, DIN_S, sw1, sb1, sw2, sb2, sg, sbt, expr_chunk);

    // prepass: dense sim on first PRE cols -> initial top-50 + threshold
    {
        dim3 g(PRE / 256, NB / 128);
        sim_gemm_kernel<<<g, 256, 0, stream>>>(
            img_norm, expr_chunk, PRE, 0, 0, 0, sim_pre, PRE,
            nullptr, nullptr, nullptr, nullptr, nullptr);
        topk_init_kernel<<<NB, 256, 0, stream>>>(sim_pre, PRE, PRE, stateV, stateI, cnt);
    }

    // chunk 0 remainder (cols PRE..CHUNK), filtered
    {
        dim3 g((CHUNK - PRE) / 256, NB / 128);
        sim_gemm_kernel<<<g, 256, 0, stream>>>(
            img_norm, expr_chunk, CHUNK, PRE, 0, 1, nullptr, 0,
            stateV, stateI, survV, survI, cnt);
        surv_merge_kernel<<<NB, 64, 0, stream>>>(survV, survI, cnt, stateV, stateI);
    }

    // chunks 1..7
    for (int c = 1; c < NCHUNK; ++c) {
        int c0 = c * CHUNK;
        int rows = (NTOT - c0 < CHUNK) ? (NTOT - c0) : CHUNK;
        proj_head_kernel<<<(rows + 63) / 64, 256, 0, stream>>>(
            all_expr + (size_t)c0 * DIN_S, rows, DIN_S,
            sw1, sb1, sw2, sb2, sg, sbt, expr_chunk);
        dim3 g((rows + 255) / 256, NB / 128);
        sim_gemm_kernel<<<g, 256, 0, stream>>>(
            img_norm, expr_chunk, rows, 0, c0, 1, nullptr, 0,
            stateV, stateI, survV, survI, cnt);
        surv_merge_kernel<<<NB, 64, 0, stream>>>(survV, survI, cnt, stateV, stateI);
    }

    finalize_kernel<<<NB, 256, 0, stream>>>(
        stateV, stateI, all_cell_type, all_expr, (float*)d_out);
}